// Round 1
// baseline (3662.323 us; speedup 1.0000x reference)
//
#include <hip/hip_runtime.h>
#include <hip/hip_bf16.h>

typedef _Float16 f16x8 __attribute__((ext_vector_type(8)));
typedef float f32x4 __attribute__((ext_vector_type(4)));
typedef unsigned int u32;
typedef unsigned long long u64;

// Problem dims
constexpr int kIN = 512;
constexpr int kHID = 1024;
constexpr int kGH = 4096;    // 4*H
constexpr int kT = 512;
constexpr int kB = 32;

constexpr u32 SENT32 = 0x7FFF7FFFu;  // f16 NaN pair; |h|<=1 can never encode this

// Workspace offsets (bytes)
constexpr size_t OFF_XG    = 0;            // [16384][4096] f16 = 134217728
constexpr size_t OFF_XH    = 134217728;    // [16384][512]  f16 = 16777216
constexpr size_t OFF_WXH   = 150994944;    // [4096][512]   f16 = 4194304
constexpr size_t OFF_WHH   = 155189248;    // [4096][1024]  f16 = 8388608
constexpr size_t OFF_BIAS  = 163577856;    // [4096]        f32 = 16384
constexpr size_t OFF_HRING = 163594240;    // [4][32][512]  u32 = 262144 (4-slot ring)
constexpr size_t WS_NEED   = 163856384;    // same as R3 (proven available)

__device__ __forceinline__ float sigm_f(float x) {
  x = fminf(fmaxf(x, -30.f), 30.f);
  return 1.f / (1.f + __expf(-x));
}
__device__ __forceinline__ float tanh_f(float x) {
  x = fminf(fmaxf(x, -15.f), 15.f);
  float e = __expf(2.f * x);
  return (e - 1.f) / (e + 1.f);
}

// ---------------------------------------------------------------------------
// K0: convert x/Wx/Wh to fp16, bias = bx+bh, sentinel-fill the h ring.
// ---------------------------------------------------------------------------
__global__ void k0_prep(const float* __restrict__ x, const float* __restrict__ Wx,
                        const float* __restrict__ bx, const float* __restrict__ Wh,
                        const float* __restrict__ bh,
                        _Float16* __restrict__ xh, _Float16* __restrict__ wxh,
                        _Float16* __restrict__ whh, float* __restrict__ bias,
                        u32* __restrict__ hring) {
  const long NX = 8388608, NWX = 2097152, NWH = 4194304, NBI = 4096, NRG = 65536;
  const long total = NX + NWX + NWH + NBI + NRG;
  for (long i = (long)blockIdx.x * blockDim.x + threadIdx.x; i < total;
       i += (long)gridDim.x * blockDim.x) {
    long j = i;
    if (j < NX) { xh[j] = (_Float16)x[j]; continue; }
    j -= NX;
    if (j < NWX) { wxh[j] = (_Float16)Wx[j]; continue; }
    j -= NWX;
    if (j < NWH) { whh[j] = (_Float16)Wh[j]; continue; }
    j -= NWH;
    if (j < NBI) { bias[j] = bx[j] + bh[j]; continue; }
    j -= NBI;
    // sentinel-fill at the coherence point (k2 reads via agent-scope loads)
    __hip_atomic_store(&hring[j], SENT32, __ATOMIC_RELAXED, __HIP_MEMORY_SCOPE_AGENT);
  }
}

// ---------------------------------------------------------------------------
// K1: xg[m][g] = sum_k xh[m][k] * wxh[g][k] + bias[g]   (B^T GEMM, fp16 MFMA)
// 128x128 tile, BK=32, 256 threads. Validated in R1-R3.
// ---------------------------------------------------------------------------
__global__ __launch_bounds__(256) void k1_xgemm(const _Float16* __restrict__ A,
                                                const _Float16* __restrict__ Bm,
                                                const float* __restrict__ bias,
                                                _Float16* __restrict__ C) {
  __shared__ _Float16 sA[128 * 32];
  __shared__ _Float16 sB[128 * 32];
  const int tid = threadIdx.x;
  const int lane = tid & 63, w = tid >> 6;
  const long m0 = (long)blockIdx.x * 128;
  const long n0 = (long)blockIdx.y * 128;
  const int wm = (w & 1) * 64, wn = (w >> 1) * 64;
  const int fr = lane & 15, fk = (lane >> 4) * 8;

  f32x4 acc[4][4] = {};

  for (int k0 = 0; k0 < kIN; k0 += 32) {
#pragma unroll
    for (int it = 0; it < 2; ++it) {
      int c = it * 256 + tid;
      int row = c >> 2, seg = c & 3;
      *(f16x8*)&sA[c * 8] = *(const f16x8*)&A[(m0 + row) * kIN + k0 + seg * 8];
      *(f16x8*)&sB[c * 8] = *(const f16x8*)&Bm[(n0 + row) * kIN + k0 + seg * 8];
    }
    __syncthreads();
    f16x8 af[4], bf[4];
#pragma unroll
    for (int t = 0; t < 4; ++t) {
      af[t] = *(const f16x8*)&sA[(wm + t * 16 + fr) * 32 + fk];
      bf[t] = *(const f16x8*)&sB[(wn + t * 16 + fr) * 32 + fk];
    }
#pragma unroll
    for (int mt = 0; mt < 4; ++mt)
#pragma unroll
      for (int nt = 0; nt < 4; ++nt)
        acc[mt][nt] = __builtin_amdgcn_mfma_f32_16x16x32_f16(af[mt], bf[nt], acc[mt][nt], 0, 0, 0);
    __syncthreads();
  }

  const int cn = lane & 15, cm4 = (lane >> 4) * 4;
#pragma unroll
  for (int nt = 0; nt < 4; ++nt) {
    long col = n0 + wn + nt * 16 + cn;
    float bv = bias[col];
#pragma unroll
    for (int mt = 0; mt < 4; ++mt)
#pragma unroll
      for (int r = 0; r < 4; ++r) {
        long row = m0 + wm + mt * 16 + cm4 + r;
        C[row * kGH + col] = (_Float16)(acc[mt][nt][r] + bv);
      }
  }
}

// ---------------------------------------------------------------------------
// K2: persistent recurrent kernel, FLAGLESS sentinel sync. 64 blocks x 256 thr.
// Ring of 4 h-slots (64KB each). Per step t a block:
//   - resets ITS OWN chunk of slot (t+1)&3 to sentinel (top of step),
//   - bulk-loads ALL 8 k-chunks of slot (t-1)&3 once, then accepts and
//     CONSUMES each chunk (MFMA) as soon as it is fresh; only stale chunks
//     (4 u64/lane = 8KB/block) are re-polled -- not the whole 64KB slot.
//     Acceptance criterion per word is identical to the proven R3 kernel,
//     so the ring-depth-4 drift proof is unchanged (full slot still accepted
//     before this step's publish).
//   - drains vmcnt(0) right after acceptance (free: poll just drained its own
//     loads; reset/out/xg-prefetch are a step old) -> publish needs no wait,
//   - computes gates via LDS reduce + elementwise, publishes h (relaxed
//     agent-scope stores, no flag), stores out, THEN barriers for `part`.
// Safety: ring depth 4 covers the 1-step drift bound (a reader accepts slot
// t-1 only when all 64 chunks are fresh => all blocks passed publish(t-1));
// reset->publish same-address coherence prevents stale acceptance; the
// vmcnt(0) drain at step t orders reset(t, slot t+1) before publish(t+1).
// ---------------------------------------------------------------------------
__global__ __launch_bounds__(256, 1) void k2_rec(const _Float16* __restrict__ xg,
                                                 const _Float16* __restrict__ whh,
                                                 u32* __restrict__ hring,
                                                 float* __restrict__ out) {
  const int tid = threadIdx.x;
  const int lane = tid & 63, w = tid >> 6;
  const int bid = blockIdx.x;    // 0..63
  const int jb = bid * 16;

  __shared__ float part[4 * 64 * 35];  // [wave][n(64)][m pad 35]

  const int fr = lane & 15;
  const int fq = lane >> 4;

  // Preload B-fragments (Wh slice stays register/AGPR-resident for the scan)
  f16x8 bfr[4][8];
#pragma unroll
  for (int nt = 0; nt < 4; ++nt) {
    long grow = (long)(nt * kHID + jb + fr) * kHID;
#pragma unroll
    for (int kt = 0; kt < 8; ++kt)
      bfr[nt][kt] = *(const f16x8*)&whh[grow + w * 256 + kt * 32 + fq * 8];
  }

  // Elementwise ownership: b = tid>>3 (0..31), jp = tid&7 -> j = jb + jp*2 + {0,1}
  const int eb = tid >> 3;
  const int jp = tid & 7;
  float cst0 = 0.f, cst1 = 0.f;

  for (int t = 0; t < kT; ++t) {
    const int wslot = t & 3, rslot = (t - 1) & 3, zslot = (t + 1) & 3;

    // Reset own chunk of slot (t+1)&3 to sentinel (readers of its old data
    // finished at step t-2; see header proof). Issued early -> lands long
    // before the post-poll vmcnt drain makes it ordered vs publish(t+1).
    __hip_atomic_store(&hring[zslot * 16384 + eb * 512 + bid * 8 + jp], SENT32,
                       __ATOMIC_RELAXED, __HIP_MEMORY_SCOPE_AGENT);

    // Prefetch xg for this step (independent of h -> in flight during poll)
    u32 xv[4];
    {
      const u32* xgu = (const u32*)xg;
      long rowbase = ((long)eb * kT + t) * (kGH / 2) + bid * 8 + jp;
#pragma unroll
      for (int g = 0; g < 4; ++g) xv[g] = xgu[rowbase + g * (kHID / 2)];
    }

    f32x4 acc[2][4] = {};
    if (t > 0) {
      const u64* hp64 = (const u64*)(hring + rslot * 16384);
      u64 hr[2][8][2];
      // Bulk-load all 8 chunks once (single latency in the common fresh case).
#pragma unroll
      for (int kt = 0; kt < 8; ++kt) {
        int cidx = w * 64 + kt * 8 + fq * 2;
#pragma unroll
        for (int q = 0; q < 2; ++q) {
          hr[0][kt][q] = __hip_atomic_load(&hp64[(size_t)fr * 256 + cidx + q],
                                           __ATOMIC_RELAXED, __HIP_MEMORY_SCOPE_AGENT);
          hr[1][kt][q] = __hip_atomic_load(&hp64[(size_t)(fr + 16) * 256 + cidx + q],
                                           __ATOMIC_RELAXED, __HIP_MEMORY_SCOPE_AGENT);
        }
      }
      // Accept-and-consume per chunk; re-poll only stale chunks.
      u32 pending = 0xFFu;  // wave-uniform (built from __any)
      while (true) {
        u32 still = 0;
#pragma unroll
        for (int kt = 0; kt < 8; ++kt) {
          if (!(pending & (1u << kt))) continue;  // uniform branch
          u32 bad = 0;
#pragma unroll
          for (int m = 0; m < 2; ++m)
#pragma unroll
            for (int q = 0; q < 2; ++q) {
              u64 v = hr[m][kt][q];
              bad |= ((u32)v == SENT32) | ((u32)(v >> 32) == SENT32);
            }
          if (__any(bad)) { still |= 1u << kt; continue; }
          // Chunk kt fresh across the wave: consume it now.
          union { u64 u[2]; f16x8 v; } ua, ub;
          ua.u[0] = hr[0][kt][0]; ua.u[1] = hr[0][kt][1];
          ub.u[0] = hr[1][kt][0]; ub.u[1] = hr[1][kt][1];
#pragma unroll
          for (int nt = 0; nt < 4; ++nt) {
            acc[0][nt] = __builtin_amdgcn_mfma_f32_16x16x32_f16(ua.v, bfr[nt][kt], acc[0][nt], 0, 0, 0);
            acc[1][nt] = __builtin_amdgcn_mfma_f32_16x16x32_f16(ub.v, bfr[nt][kt], acc[1][nt], 0, 0, 0);
          }
        }
        pending = still;
        if (!pending) break;
        __builtin_amdgcn_s_sleep(1);
        asm volatile("" ::: "memory");
        // Reload only the stale chunks (8KB/block instead of 64KB).
#pragma unroll
        for (int kt = 0; kt < 8; ++kt) {
          if (!(pending & (1u << kt))) continue;
          int cidx = w * 64 + kt * 8 + fq * 2;
#pragma unroll
          for (int q = 0; q < 2; ++q) {
            hr[0][kt][q] = __hip_atomic_load(&hp64[(size_t)fr * 256 + cidx + q],
                                             __ATOMIC_RELAXED, __HIP_MEMORY_SCOPE_AGENT);
            hr[1][kt][q] = __hip_atomic_load(&hp64[(size_t)(fr + 16) * 256 + cidx + q],
                                             __ATOMIC_RELAXED, __HIP_MEMORY_SCOPE_AGENT);
          }
        }
      }
      // Drain here, off the publish path. Covers: reset(t, slot t+1), the
      // out store of step t-1, xg prefetch, and the poll's own loads (done).
      // No vmem is issued between here and publish -> publish needs no wait.
      asm volatile("s_waitcnt vmcnt(0)" ::: "memory");
    }

    // Store partials: n = nt*16 + fr, m = mt*16 + fq*4 + r
#pragma unroll
    for (int mt = 0; mt < 2; ++mt)
#pragma unroll
      for (int nt = 0; nt < 4; ++nt)
        *(f32x4*)&part[(w * 64 + nt * 16 + fr) * 35 + mt * 16 + fq * 4] = acc[mt][nt];
    __syncthreads();

    // Reduce partials + elementwise LSTM for (eb, jp*2) and (eb, jp*2+1)
    float g0[4], g1[4];
#pragma unroll
    for (int g = 0; g < 4; ++g) {
      union { u32 u; _Float16 h[2]; } xu;
      xu.u = xv[g];
      float s0 = (float)xu.h[0], s1 = (float)xu.h[1];
      int n0 = g * 16 + jp * 2;
#pragma unroll
      for (int wv = 0; wv < 4; ++wv) {
        s0 += part[(wv * 64 + n0) * 35 + eb];
        s1 += part[(wv * 64 + n0 + 1) * 35 + eb];
      }
      g0[g] = s0; g1[g] = s1;
    }

    float h0, h1;
    {
      float ig = sigm_f(g0[0]), fg = sigm_f(g0[1]);
      float gg = tanh_f(g0[2]), og = sigm_f(g0[3]);
      cst0 = cst0 * fg + ig * gg;
      h0 = og * tanh_f(cst0);
    }
    {
      float ig = sigm_f(g1[0]), fg = sigm_f(g1[1]);
      float gg = tanh_f(g1[2]), og = sigm_f(g1[3]);
      cst1 = cst1 * fg + ig * gg;
      h1 = og * tanh_f(cst1);
    }

    // Publish h into slot t&3 immediately: relaxed agent-scope store, NO flag,
    // NO wait (drain already happened post-poll; nothing vmem since).
    union { u32 u; _Float16 h[2]; } pk;
    pk.h[0] = (_Float16)h0; pk.h[1] = (_Float16)h1;
    __hip_atomic_store(&hring[wslot * 16384 + eb * 512 + bid * 8 + jp],
                       pk.u, __ATOMIC_RELAXED, __HIP_MEMORY_SCOPE_AGENT);

    // out store after publish: completion off the critical path.
    *(float2*)&out[((long)eb * kT + t) * kHID + jb + jp * 2] = make_float2(h0, h1);

    // Barrier last: separates this step's `part` reads from next step's writes,
    // and is off the publish critical path.
    __syncthreads();
  }
}

// ---------------------------------------------------------------------------
extern "C" void kernel_launch(void* const* d_in, const int* in_sizes, int n_in,
                              void* d_out, int out_size, void* d_ws, size_t ws_size,
                              hipStream_t stream) {
  const float* x  = (const float*)d_in[0];
  const float* Wx = (const float*)d_in[1];
  const float* bx = (const float*)d_in[2];
  const float* Wh = (const float*)d_in[3];
  const float* bh = (const float*)d_in[4];
  float* out = (float*)d_out;

  if (ws_size < WS_NEED) return;

  char* ws = (char*)d_ws;
  _Float16* xg    = (_Float16*)(ws + OFF_XG);
  _Float16* xh    = (_Float16*)(ws + OFF_XH);
  _Float16* wxh   = (_Float16*)(ws + OFF_WXH);
  _Float16* whh   = (_Float16*)(ws + OFF_WHH);
  float*    bias  = (float*)(ws + OFF_BIAS);
  u32*      hring = (u32*)(ws + OFF_HRING);

  hipLaunchKernelGGL(k0_prep, dim3(4096), dim3(256), 0, stream,
                     x, Wx, bx, Wh, bh, xh, wxh, whh, bias, hring);
  hipLaunchKernelGGL(k1_xgemm, dim3(128, 32), dim3(256), 0, stream,
                     xh, wxh, bias, xg);
  hipLaunchKernelGGL(k2_rec, dim3(64), dim3(256), 0, stream,
                     xg, whh, hring, out);
}